// Round 6
// baseline (1039.227 us; speedup 1.0000x reference)
//
#include <hip/hip_runtime.h>

// VQ-VAE vector quantizer forward (fp32).
// inputs: (32,256,32,32) f32 -> flat rows N=32768 x D=256
// embedding: (D=256, K=1024) f32, cluster_size: (1024,) f32
// outputs (flat f32): quantized[N*D], vq_loss, perplexity, code_usage, indices[N] (as float)

constexpr int DIM = 256;   // embedding dim
constexpr int NK  = 1024;  // number of codes
constexpr int RR  = 32;    // input rows per block (16 per wave-pair)
constexpr int NH  = DIM / 2;  // 128 two-dim groups

// async 16B global->LDS. HW dest = wave-uniform base + lane*16; all call
// sites pass base + 16*lane exactly.
#define GLL16(GSRC, LDST)                                                      \
  __builtin_amdgcn_global_load_lds(                                            \
      (const __attribute__((address_space(1))) void*)(GSRC),                   \
      (__attribute__((address_space(3))) void*)(LDST), 16, 0, 0)

// ---------------------------------------------------------------- enorm (0.5*|e_k|^2)
__global__ __launch_bounds__(256) void enorm_kernel(
    const float* __restrict__ emb, float* __restrict__ enorm) {
  int k = blockIdx.x * 256 + threadIdx.x;
  float s = 0.f;
  for (int d = 0; d < DIM; ++d) {
    float e = emb[(size_t)d * NK + k];
    s = fmaf(e, e, s);
  }
  enorm[k] = 0.5f * s;                   // argmin(|e|^2-2x.e) == argmin(0.5|e|^2-x.e)
}

// ---------------------------------------------------------------- argmin
// 256 threads = 4 waves. Waves 0,1 -> rows 0-15; waves 2,3 -> rows 16-31.
// Lane owns codes {c_lo..c_lo+3} u {c_hi..c_hi+3}, c_lo=256*(wv&1)+4*lane,
// c_hi=c_lo+512 -> waves w,w^1 jointly cover all 1024 codes for their rows.
// Each wave stages ITS OWN es slice (self-staged => no barriers in loop;
// per-wave counted vmcnt keeps next group's 4 loads in flight). Waves {0,2}
// stage duplicate data into separate slices — no cross-wave reuse race.
__global__ __launch_bounds__(256, 2) void argmin_kernel(
    const float* __restrict__ x, const float* __restrict__ emb,
    const float* __restrict__ enorm, int* __restrict__ idx_out,
    float* __restrict__ idx_out_f) {
  __shared__ float xs[RR * DIM];         // 32 KB x-tile
  __shared__ float es[2][4][2][512];     // 32 KB: [parity][wave][dim][lo256|hi256]
  __shared__ float red_v[4][16];
  __shared__ int   red_i[4][16];

  const int tid   = threadIdx.x;
  const int lane  = tid & 63;
  const int wv    = tid >> 6;
  const int rbase = (wv >> 1) * 16;
  const int c_lo  = 256 * (wv & 1) + 4 * lane;
  const int c_hi  = c_lo + 512;
  const size_t xbase = (size_t)blockIdx.x * (RR * DIM);

  // stage x-tile (block-wide, cross-wave reads -> barrier below)
  #pragma unroll
  for (int i = 0; i < 8; ++i)
    GLL16(x + xbase + (size_t)(tid + 256 * i) * 4, &xs[(tid + 256 * i) * 4]);
  // stage es group 0 (dims 0,1), per-wave slice
  #pragma unroll
  for (int d = 0; d < 2; ++d) {
    GLL16(emb + (size_t)d * NK + c_lo, &es[0][wv][d][4 * lane]);
    GLL16(emb + (size_t)d * NK + c_hi, &es[0][wv][d][256 + 4 * lane]);
  }
  __syncthreads();   // drains vmcnt(0): x-tile + group 0 resident

  float acc[16][8];
  #pragma unroll
  for (int r = 0; r < 16; ++r)
    #pragma unroll
    for (int j = 0; j < 8; ++j) acc[r][j] = 0.f;

  float4 xv[16];   // 4-dim x values, reused across an even/odd h pair

  #pragma unroll 2
  for (int h = 0; h < NH; ++h) {
    if (h < NH - 1) {
      const float* s0 = emb + (size_t)(2 * (h + 1)) * NK;
      const int p = (h + 1) & 1;
      GLL16(s0 + c_lo,      &es[p][wv][0][4 * lane]);
      GLL16(s0 + c_hi,      &es[p][wv][0][256 + 4 * lane]);
      GLL16(s0 + NK + c_lo, &es[p][wv][1][4 * lane]);
      GLL16(s0 + NK + c_hi, &es[p][wv][1][256 + 4 * lane]);
      asm volatile("s_waitcnt vmcnt(4)" ::: "memory");  // group h landed; h+1 in flight
    } else {
      asm volatile("s_waitcnt vmcnt(0)" ::: "memory");
    }
    __builtin_amdgcn_sched_barrier(0);

    const int p = h & 1;
    const float4 el0 = *(const float4*)&es[p][wv][0][4 * lane];
    const float4 eh0 = *(const float4*)&es[p][wv][0][256 + 4 * lane];
    const float4 el1 = *(const float4*)&es[p][wv][1][4 * lane];
    const float4 eh1 = *(const float4*)&es[p][wv][1][256 + 4 * lane];

    if ((h & 1) == 0) {   // static under unroll 2
      #pragma unroll
      for (int r = 0; r < 16; ++r)
        xv[r] = *(const float4*)&xs[(rbase + r) * DIM + (h >> 1) * 4];  // broadcast
    }
    #pragma unroll
    for (int r = 0; r < 16; ++r) {
      const float xa = ((h & 1) == 0) ? xv[r].x : xv[r].z;
      const float xb = ((h & 1) == 0) ? xv[r].y : xv[r].w;
      acc[r][0] = fmaf(xa, el0.x, fmaf(xb, el1.x, acc[r][0]));
      acc[r][1] = fmaf(xa, el0.y, fmaf(xb, el1.y, acc[r][1]));
      acc[r][2] = fmaf(xa, el0.z, fmaf(xb, el1.z, acc[r][2]));
      acc[r][3] = fmaf(xa, el0.w, fmaf(xb, el1.w, acc[r][3]));
      acc[r][4] = fmaf(xa, eh0.x, fmaf(xb, eh1.x, acc[r][4]));
      acc[r][5] = fmaf(xa, eh0.y, fmaf(xb, eh1.y, acc[r][5]));
      acc[r][6] = fmaf(xa, eh0.z, fmaf(xb, eh1.z, acc[r][6]));
      acc[r][7] = fmaf(xa, eh0.w, fmaf(xb, eh1.w, acc[r][7]));
    }
  }

  const float4 enl = *(const float4*)(enorm + c_lo);   // 0.5*|e|^2
  const float4 enh = *(const float4*)(enorm + c_hi);

  for (int r = 0; r < 16; ++r) {
    // score = 0.5|e|^2 - x.e ; lowest index wins ties (c_lo quad first)
    float bv = enl.x - acc[r][0];
    int   bi = c_lo;
    { float v = enl.y - acc[r][1]; if (v < bv) { bv = v; bi = c_lo + 1; } }
    { float v = enl.z - acc[r][2]; if (v < bv) { bv = v; bi = c_lo + 2; } }
    { float v = enl.w - acc[r][3]; if (v < bv) { bv = v; bi = c_lo + 3; } }
    { float v = enh.x - acc[r][4]; if (v < bv) { bv = v; bi = c_hi; } }
    { float v = enh.y - acc[r][5]; if (v < bv) { bv = v; bi = c_hi + 1; } }
    { float v = enh.z - acc[r][6]; if (v < bv) { bv = v; bi = c_hi + 2; } }
    { float v = enh.w - acc[r][7]; if (v < bv) { bv = v; bi = c_hi + 3; } }
    for (int off = 32; off > 0; off >>= 1) {
      float ov = __shfl_xor(bv, off);
      int   oi = __shfl_xor(bi, off);
      if (ov < bv || (ov == bv && oi < bi)) { bv = ov; bi = oi; }
    }
    if (lane == 0) { red_v[wv][r] = bv; red_i[wv][r] = bi; }
  }
  __syncthreads();

  if (tid < 32) {
    const int row = tid & 15;
    const int w0  = (tid >> 4) * 2;     // rows 0-15 <- waves 0,1; 16-31 <- 2,3
    float bv = red_v[w0][row];
    int   bi = red_i[w0][row];
    { float v = red_v[w0 + 1][row]; int i2 = red_i[w0 + 1][row];
      if (v < bv || (v == bv && i2 < bi)) { bv = v; bi = i2; } }
    const int n = blockIdx.x * RR + tid;
    idx_out[n]   = bi;
    idx_out_f[n] = (float)bi;
  }
}

// ---------------------------------------------------------------- gather + loss partials
__global__ __launch_bounds__(256) void gather_loss_kernel(
    const float* __restrict__ x, const float* __restrict__ emb,
    const int* __restrict__ idx, float* __restrict__ out_q,
    float* __restrict__ partial) {
  const int tid = threadIdx.x;
  const size_t base = (size_t)blockIdx.x * 2048;
  float local = 0.f;
  #pragma unroll
  for (int h = 0; h < 2; ++h) {
    const size_t g = base + (size_t)h * 1024 + (size_t)tid * 4;
    const int n = (int)(g >> 8);
    const int d = (int)(g & 255);
    const int k = idx[n];
    const float* ep = emb + (size_t)d * NK + k;
    float4 q;
    q.x = ep[0]; q.y = ep[NK]; q.z = ep[2 * NK]; q.w = ep[3 * NK];
    const float4 xv = *(const float4*)(x + g);
    *(float4*)(out_q + g) = q;
    const float dx = q.x - xv.x, dy = q.y - xv.y, dz = q.z - xv.z, dw = q.w - xv.w;
    local = fmaf(dx, dx, local);
    local = fmaf(dy, dy, local);
    local = fmaf(dz, dz, local);
    local = fmaf(dw, dw, local);
  }
  for (int off = 32; off > 0; off >>= 1) local += __shfl_down(local, off);
  __shared__ float wsum[4];
  if ((tid & 63) == 0) wsum[tid >> 6] = local;
  __syncthreads();
  if (tid == 0) partial[blockIdx.x] = (wsum[0] + wsum[1]) + (wsum[2] + wsum[3]);
}

// ---------------------------------------------------------------- finalize scalars
__global__ __launch_bounds__(1024) void finalize_kernel(
    const float* __restrict__ partial, int np,
    const float* __restrict__ cs, float* __restrict__ out_s,
    float inv_count) {
  __shared__ float sd[1024];
  const int tid = threadIdx.x;

  float s = 0.f;
  for (int i = tid; i < np; i += 1024) s += partial[i];
  sd[tid] = s; __syncthreads();
  for (int st = 512; st > 0; st >>= 1) {
    if (tid < st) sd[tid] += sd[tid + st];
    __syncthreads();
  }
  const float total_sq = sd[0];
  __syncthreads();

  const float c = cs[tid];
  sd[tid] = c; __syncthreads();
  for (int st = 512; st > 0; st >>= 1) {
    if (tid < st) sd[tid] += sd[tid + st];
    __syncthreads();
  }
  const float S = sd[0];
  __syncthreads();

  const float p = c / (S + 1e-5f);
  sd[tid] = p * logf(p + 1e-5f);
  __syncthreads();
  for (int st = 512; st > 0; st >>= 1) {
    if (tid < st) sd[tid] += sd[tid + st];
    __syncthreads();
  }
  const float T = sd[0];
  __syncthreads();

  sd[tid] = (c > 1e-5f) ? 1.f : 0.f;
  __syncthreads();
  for (int st = 512; st > 0; st >>= 1) {
    if (tid < st) sd[tid] += sd[tid + st];
    __syncthreads();
  }
  const float U = sd[0];

  if (tid == 0) {
    out_s[0] = 1.25f * total_sq * inv_count;  // e_latent + 0.25*q_latent
    out_s[1] = expf(-T);                      // perplexity
    out_s[2] = U * (1.f / 1024.f);            // code usage rate
  }
}

// ---------------------------------------------------------------- launch
extern "C" void kernel_launch(void* const* d_in, const int* in_sizes, int n_in,
                              void* d_out, int out_size, void* d_ws, size_t ws_size,
                              hipStream_t stream) {
  const float* x   = (const float*)d_in[0];
  const float* emb = (const float*)d_in[1];
  const float* cs  = (const float*)d_in[2];
  float* out = (float*)d_out;

  const int N = in_sizes[0] / DIM;          // 32768
  const size_t ND = (size_t)N * DIM;        // 8388608

  float* enorm   = (float*)d_ws;                                           // 4 KB
  int*   idxw    = (int*)((char*)d_ws + NK * sizeof(float));               // 128 KB
  float* partial = (float*)((char*)d_ws + NK * sizeof(float) + (size_t)N * sizeof(int)); // 16 KB

  const int nGather = (int)(ND / 2048);     // 4096

  enorm_kernel<<<NK / 256, 256, 0, stream>>>(emb, enorm);
  argmin_kernel<<<N / RR, 256, 0, stream>>>(x, emb, enorm, idxw, out + ND + 3);
  gather_loss_kernel<<<nGather, 256, 0, stream>>>(x, emb, idxw, out, partial);
  finalize_kernel<<<1, 1024, 0, stream>>>(partial, nGather, cs, out + ND,
                                          1.0f / (float)ND);
}

// Round 7
// 324.690 us; speedup vs baseline: 3.2007x; 3.2007x over previous
//
#include <hip/hip_runtime.h>

// VQ-VAE vector quantizer forward (fp32).
// inputs: (32,256,32,32) f32 -> flat rows N=32768 x D=256
// embedding: (D=256, K=1024) f32, cluster_size: (1024,) f32
// outputs (flat f32): quantized[N*D], vq_loss, perplexity, code_usage, indices[N] (as float)

constexpr int DIM = 256;   // embedding dim
constexpr int NK  = 1024;  // number of codes
constexpr int RR  = 16;    // input rows per block
constexpr int NG  = DIM / 4;  // 64 four-dim groups

// async 16B global->LDS. HW dest = wave-uniform base + lane*16; every call
// site passes exactly base + 16*lane. Global src addr is per-lane (allowed).
#define GLL16(GSRC, LDST)                                                      \
  __builtin_amdgcn_global_load_lds(                                            \
      (const __attribute__((address_space(1))) void*)(GSRC),                   \
      (__attribute__((address_space(3))) void*)(LDST), 16, 0, 0)

// ---------------------------------------------------------------- enorm (0.5*|e_k|^2)
__global__ __launch_bounds__(256) void enorm_kernel(
    const float* __restrict__ emb, float* __restrict__ enorm) {
  int k = blockIdx.x * 256 + threadIdx.x;
  float s = 0.f;
  for (int d = 0; d < DIM; ++d) {
    float e = emb[(size_t)d * NK + k];
    s = fmaf(e, e, s);
  }
  enorm[k] = 0.5f * s;                   // argmin(|e|^2-2x.e) == argmin(0.5|e|^2-x.e)
}

// ---------------------------------------------------------------- argmin
// 128 threads = 2 waves, 16 rows/block, lane owns 8 codes:
//   c_lo = 256*wv + 4*lane (quad), c_hi = c_lo + 512 (quad) -> 2 waves cover 1024.
// Per 4-dim group: 16 xs broadcast reads + 8 es reads + 512 FMAs (ratio 21.3
// vs R5's 12.8). es per-wave slice is self-staged via global_load_lds ->
// NO in-loop barriers; counted vmcnt(8) keeps next group's loads in flight.
// No loop-carried register arrays except acc (R6 spill lesson).
__global__ __launch_bounds__(128, 2) void argmin_kernel(
    const float* __restrict__ x, const float* __restrict__ emb,
    const float* __restrict__ enorm, int* __restrict__ idx_out,
    float* __restrict__ idx_out_f) {
  __shared__ float xs[RR * DIM];         // 16 KB x-tile
  __shared__ float es[2][2][4][512];     // 32 KB: [parity][wave][dim][lo256|hi256]
  __shared__ float red_v[2][RR];
  __shared__ int   red_i[2][RR];

  const int tid  = threadIdx.x;
  const int lane = tid & 63;
  const int wv   = tid >> 6;
  const int c_lo = 256 * wv + 4 * lane;
  const int c_hi = c_lo + 512;
  const size_t xbase = (size_t)blockIdx.x * (RR * DIM);

  // stage x-tile: thread t covers float-offsets 4*(t+128i), i=0..7
  // (per wave: uniform base + lane*16 ✓)
  #pragma unroll
  for (int i = 0; i < 8; ++i)
    GLL16(x + xbase + (size_t)(tid + 128 * i) * 4, &xs[(tid + 128 * i) * 4]);
  // stage es group 0 (dims 0..3), per-wave slice
  #pragma unroll
  for (int d = 0; d < 4; ++d) {
    GLL16(emb + (size_t)d * NK + c_lo, &es[0][wv][d][4 * lane]);
    GLL16(emb + (size_t)d * NK + c_hi, &es[0][wv][d][256 + 4 * lane]);
  }
  __syncthreads();   // drains vmcnt(0): x-tile + group 0 resident

  float acc[RR][8];
  #pragma unroll
  for (int r = 0; r < RR; ++r)
    #pragma unroll
    for (int j = 0; j < 8; ++j) acc[r][j] = 0.f;

  for (int g = 0; g < NG; ++g) {
    if (g < NG - 1) {
      const float* s0 = emb + (size_t)(4 * (g + 1)) * NK;
      const int p = (g + 1) & 1;
      #pragma unroll
      for (int d = 0; d < 4; ++d) {
        GLL16(s0 + (size_t)d * NK + c_lo, &es[p][wv][d][4 * lane]);
        GLL16(s0 + (size_t)d * NK + c_hi, &es[p][wv][d][256 + 4 * lane]);
      }
      asm volatile("s_waitcnt vmcnt(8)" ::: "memory");  // group g landed; g+1 (8) in flight
    } else {
      asm volatile("s_waitcnt vmcnt(0)" ::: "memory");
    }
    __builtin_amdgcn_sched_barrier(0);

    const int b = g & 1;
    const float4 l0 = *(const float4*)&es[b][wv][0][4 * lane];
    const float4 l1 = *(const float4*)&es[b][wv][1][4 * lane];
    const float4 l2 = *(const float4*)&es[b][wv][2][4 * lane];
    const float4 l3 = *(const float4*)&es[b][wv][3][4 * lane];
    const float4 h0 = *(const float4*)&es[b][wv][0][256 + 4 * lane];
    const float4 h1 = *(const float4*)&es[b][wv][1][256 + 4 * lane];
    const float4 h2 = *(const float4*)&es[b][wv][2][256 + 4 * lane];
    const float4 h3 = *(const float4*)&es[b][wv][3][256 + 4 * lane];

    #pragma unroll
    for (int r = 0; r < RR; ++r) {
      const float4 xv = *(const float4*)&xs[r * DIM + 4 * g];   // broadcast
      acc[r][0] = fmaf(xv.x, l0.x, fmaf(xv.y, l1.x, fmaf(xv.z, l2.x, fmaf(xv.w, l3.x, acc[r][0]))));
      acc[r][1] = fmaf(xv.x, l0.y, fmaf(xv.y, l1.y, fmaf(xv.z, l2.y, fmaf(xv.w, l3.y, acc[r][1]))));
      acc[r][2] = fmaf(xv.x, l0.z, fmaf(xv.y, l1.z, fmaf(xv.z, l2.z, fmaf(xv.w, l3.z, acc[r][2]))));
      acc[r][3] = fmaf(xv.x, l0.w, fmaf(xv.y, l1.w, fmaf(xv.z, l2.w, fmaf(xv.w, l3.w, acc[r][3]))));
      acc[r][4] = fmaf(xv.x, h0.x, fmaf(xv.y, h1.x, fmaf(xv.z, h2.x, fmaf(xv.w, h3.x, acc[r][4]))));
      acc[r][5] = fmaf(xv.x, h0.y, fmaf(xv.y, h1.y, fmaf(xv.z, h2.y, fmaf(xv.w, h3.y, acc[r][5]))));
      acc[r][6] = fmaf(xv.x, h0.z, fmaf(xv.y, h1.z, fmaf(xv.z, h2.z, fmaf(xv.w, h3.z, acc[r][6]))));
      acc[r][7] = fmaf(xv.x, h0.w, fmaf(xv.y, h1.w, fmaf(xv.z, h2.w, fmaf(xv.w, h3.w, acc[r][7]))));
    }
  }

  const float4 enl = *(const float4*)(enorm + c_lo);   // 0.5*|e|^2
  const float4 enh = *(const float4*)(enorm + c_hi);

  for (int r = 0; r < RR; ++r) {
    // score = 0.5|e|^2 - x.e ; strict < keeps lowest index on ties
    float bv = enl.x - acc[r][0];
    int   bi = c_lo;
    { float v = enl.y - acc[r][1]; if (v < bv) { bv = v; bi = c_lo + 1; } }
    { float v = enl.z - acc[r][2]; if (v < bv) { bv = v; bi = c_lo + 2; } }
    { float v = enl.w - acc[r][3]; if (v < bv) { bv = v; bi = c_lo + 3; } }
    { float v = enh.x - acc[r][4]; if (v < bv) { bv = v; bi = c_hi; } }
    { float v = enh.y - acc[r][5]; if (v < bv) { bv = v; bi = c_hi + 1; } }
    { float v = enh.z - acc[r][6]; if (v < bv) { bv = v; bi = c_hi + 2; } }
    { float v = enh.w - acc[r][7]; if (v < bv) { bv = v; bi = c_hi + 3; } }
    for (int off = 32; off > 0; off >>= 1) {
      float ov = __shfl_xor(bv, off);
      int   oi = __shfl_xor(bi, off);
      if (ov < bv || (ov == bv && oi < bi)) { bv = ov; bi = oi; }
    }
    if (lane == 0) { red_v[wv][r] = bv; red_i[wv][r] = bi; }
  }
  __syncthreads();

  if (tid < RR) {
    float bv = red_v[0][tid];
    int   bi = red_i[0][tid];
    { float v = red_v[1][tid]; int i2 = red_i[1][tid];
      if (v < bv || (v == bv && i2 < bi)) { bv = v; bi = i2; } }
    const int n = blockIdx.x * RR + tid;
    idx_out[n]   = bi;
    idx_out_f[n] = (float)bi;
  }
}

// ---------------------------------------------------------------- gather + loss partials
__global__ __launch_bounds__(256) void gather_loss_kernel(
    const float* __restrict__ x, const float* __restrict__ emb,
    const int* __restrict__ idx, float* __restrict__ out_q,
    float* __restrict__ partial) {
  const int tid = threadIdx.x;
  const size_t base = (size_t)blockIdx.x * 2048;
  float local = 0.f;
  #pragma unroll
  for (int h = 0; h < 2; ++h) {
    const size_t g = base + (size_t)h * 1024 + (size_t)tid * 4;
    const int n = (int)(g >> 8);
    const int d = (int)(g & 255);
    const int k = idx[n];
    const float* ep = emb + (size_t)d * NK + k;
    float4 q;
    q.x = ep[0]; q.y = ep[NK]; q.z = ep[2 * NK]; q.w = ep[3 * NK];
    const float4 xv = *(const float4*)(x + g);
    *(float4*)(out_q + g) = q;
    const float dx = q.x - xv.x, dy = q.y - xv.y, dz = q.z - xv.z, dw = q.w - xv.w;
    local = fmaf(dx, dx, local);
    local = fmaf(dy, dy, local);
    local = fmaf(dz, dz, local);
    local = fmaf(dw, dw, local);
  }
  for (int off = 32; off > 0; off >>= 1) local += __shfl_down(local, off);
  __shared__ float wsum[4];
  if ((tid & 63) == 0) wsum[tid >> 6] = local;
  __syncthreads();
  if (tid == 0) partial[blockIdx.x] = (wsum[0] + wsum[1]) + (wsum[2] + wsum[3]);
}

// ---------------------------------------------------------------- finalize scalars
__global__ __launch_bounds__(1024) void finalize_kernel(
    const float* __restrict__ partial, int np,
    const float* __restrict__ cs, float* __restrict__ out_s,
    float inv_count) {
  __shared__ float sd[1024];
  const int tid = threadIdx.x;

  float s = 0.f;
  for (int i = tid; i < np; i += 1024) s += partial[i];
  sd[tid] = s; __syncthreads();
  for (int st = 512; st > 0; st >>= 1) {
    if (tid < st) sd[tid] += sd[tid + st];
    __syncthreads();
  }
  const float total_sq = sd[0];
  __syncthreads();

  const float c = cs[tid];
  sd[tid] = c; __syncthreads();
  for (int st = 512; st > 0; st >>= 1) {
    if (tid < st) sd[tid] += sd[tid + st];
    __syncthreads();
  }
  const float S = sd[0];
  __syncthreads();

  const float p = c / (S + 1e-5f);
  sd[tid] = p * logf(p + 1e-5f);
  __syncthreads();
  for (int st = 512; st > 0; st >>= 1) {
    if (tid < st) sd[tid] += sd[tid + st];
    __syncthreads();
  }
  const float T = sd[0];
  __syncthreads();

  sd[tid] = (c > 1e-5f) ? 1.f : 0.f;
  __syncthreads();
  for (int st = 512; st > 0; st >>= 1) {
    if (tid < st) sd[tid] += sd[tid + st];
    __syncthreads();
  }
  const float U = sd[0];

  if (tid == 0) {
    out_s[0] = 1.25f * total_sq * inv_count;  // e_latent + 0.25*q_latent
    out_s[1] = expf(-T);                      // perplexity
    out_s[2] = U * (1.f / 1024.f);            // code usage rate
  }
}

// ---------------------------------------------------------------- launch
extern "C" void kernel_launch(void* const* d_in, const int* in_sizes, int n_in,
                              void* d_out, int out_size, void* d_ws, size_t ws_size,
                              hipStream_t stream) {
  const float* x   = (const float*)d_in[0];
  const float* emb = (const float*)d_in[1];
  const float* cs  = (const float*)d_in[2];
  float* out = (float*)d_out;

  const int N = in_sizes[0] / DIM;          // 32768
  const size_t ND = (size_t)N * DIM;        // 8388608

  float* enorm   = (float*)d_ws;                                           // 4 KB
  int*   idxw    = (int*)((char*)d_ws + NK * sizeof(float));               // 128 KB
  float* partial = (float*)((char*)d_ws + NK * sizeof(float) + (size_t)N * sizeof(int)); // 16 KB

  const int nGather = (int)(ND / 2048);     // 4096

  enorm_kernel<<<NK / 256, 256, 0, stream>>>(emb, enorm);
  argmin_kernel<<<N / RR, 128, 0, stream>>>(x, emb, enorm, idxw, out + ND + 3);
  gather_loss_kernel<<<nGather, 256, 0, stream>>>(x, emb, idxw, out, partial);
  finalize_kernel<<<1, 1024, 0, stream>>>(partial, nGather, cs, out + ND,
                                          1.0f / (float)ND);
}